// Round 7
// baseline (624.657 us; speedup 1.0000x reference)
//
#include <hip/hip_runtime.h>

// LogicGatedSNN v6: LINEAR-SWEEP restructure of both passes.
//
// Mechanism (from v1-v5 data): every prior version owned memory per
// row/block (32-KB or 128-KB power-of-2 strides between concurrently
// active 1-KB bursts). That aliases the HBM channel-interleave bits and
// scatters DRAM pages -> effective ~4.3 TB/s regardless of occupancy /
// VGPR / fusion. The harness's own fillBuffer (linear write sweep) does
// 6.5 TB/s in the same context; m13's linear copy does 6.29 TB/s.
// Fix: make the *instantaneous global footprint* a dense linear window:
// grid-stride sweeps where consecutive blocks touch consecutive 4-KB
// chunks, advancing front-to-back together.
//
//  memset: zero current[8192] in d_ws (32 KB, stream op).
//  K1 snn_gate_sweep: linear sweep of syn; per-wave butterfly over its
//     1-KB chunk (one row: 2048 f4/row, wave-aligned) -> one fp32
//     atomicAdd per wave-chunk into current[row]. Exact: integer counts.
//  K1b snn_lif: 8192 threads: v = mp*0.6 + current; spike; v_new.
//  K2 snn_trace_sweep: elementwise out=clip(tr*0.7+spike[row]*x[col]);
//     the m13 copy pattern + 2 VALU; spike wave-uniform, x L1-hot.

#define IN_F 8192
#define OUT_F 8192
#define SYN_THRESH 50.0f

typedef float vfloat4 __attribute__((ext_vector_type(4)));

#define NF4_TOTAL (1 << 24)   // 8192*8192/4 float4 in the matrix
#define NTHREADS  (1 << 19)   // 2048 blocks * 256 threads
#define NITER     (NF4_TOTAL / NTHREADS)   // 32

// ---------------- K1: gated row-sum, linear sweep + atomics ----------
__global__ __launch_bounds__(256, 8) void snn_gate_sweep(
    const float* __restrict__ x,      // [IN_F] spike_input (0/1)
    const float* __restrict__ syn,    // [OUT_F, IN_F]
    float* __restrict__ current)      // [OUT_F] accumulator (pre-zeroed)
{
    const int gtid = blockIdx.x * 256 + threadIdx.x;
    const int lane = threadIdx.x & 63;
    const vfloat4* __restrict__ syn4 = (const vfloat4*)syn;
    const vfloat4* __restrict__ x4   = (const vfloat4*)x;

#pragma unroll 1
    for (int it = 0; it < NITER; it += 4) {
        vfloat4 s[4], xx[4];
        int g[4];
#pragma unroll
        for (int u = 0; u < 4; ++u) {
            g[u]  = gtid + (it + u) * NTHREADS;             // linear sweep
            s[u]  = __builtin_nontemporal_load(&syn4[g[u]]); // one-pass stream
            xx[u] = x4[g[u] & 2047];                         // L1-hot 32 KB
        }
#pragma unroll
        for (int u = 0; u < 4; ++u) {
            float p = ((s[u].x > SYN_THRESH) ? xx[u].x : 0.0f)
                    + ((s[u].y > SYN_THRESH) ? xx[u].y : 0.0f)
                    + ((s[u].z > SYN_THRESH) ? xx[u].z : 0.0f)
                    + ((s[u].w > SYN_THRESH) ? xx[u].w : 0.0f);
            // wave's 64 consecutive float4 are within one row -> butterfly
#pragma unroll
            for (int off = 32; off > 0; off >>= 1)
                p += __shfl_xor(p, off, 64);
            if (lane == 0)
                atomicAdd(&current[g[u] >> 11], p);          // row = g/2048
        }
    }
}

// ---------------- K1b: LIF update ------------------------------------
__global__ __launch_bounds__(256) void snn_lif(
    const float* __restrict__ current,  // [OUT_F]
    const float* __restrict__ mp,       // [OUT_F]
    const float* __restrict__ thr,      // [OUT_F]
    float* __restrict__ out_spikes,     // [OUT_F]
    float* __restrict__ out_vnew)       // [OUT_F]
{
    const int i = blockIdx.x * 256 + threadIdx.x;  // 32 blocks * 256 = 8192
    const float v     = mp[i] * 0.6f + current[i];
    const float spike = (v >= thr[i]) ? 1.0f : 0.0f;
    out_spikes[i] = spike;
    out_vnew[i]   = v * (1.0f - spike) * 0.3f;
}

// ---------------- K2: trace update, linear sweep ----------------------
__global__ __launch_bounds__(256, 8) void snn_trace_sweep(
    const float* __restrict__ x,        // [IN_F]
    const float* __restrict__ trace,    // [OUT_F, IN_F]
    const float* __restrict__ spikes,   // [OUT_F] (from K1b)
    float* __restrict__ out_trace)      // [OUT_F, IN_F]
{
    const int gtid = blockIdx.x * 256 + threadIdx.x;
    const vfloat4* __restrict__ tr4 = (const vfloat4*)trace;
    const vfloat4* __restrict__ x4  = (const vfloat4*)x;
    vfloat4* __restrict__ ot4       = (vfloat4*)out_trace;

#pragma unroll 1
    for (int it = 0; it < NITER; it += 4) {
        vfloat4 t[4], xx[4];
        float sp[4];
        int g[4];
#pragma unroll
        for (int u = 0; u < 4; ++u) {
            g[u]  = gtid + (it + u) * NTHREADS;      // linear sweep
            t[u]  = tr4[g[u]];                       // LLC-dirty from restore
            xx[u] = x4[g[u] & 2047];                 // L1-hot
            sp[u] = spikes[g[u] >> 11];              // wave-uniform
        }
#pragma unroll
        for (int u = 0; u < 4; ++u) {
            vfloat4 o;
            o.x = fminf(fmaxf(fmaf(t[u].x, 0.7f, sp[u] * xx[u].x), 0.0f), 3.0f);
            o.y = fminf(fmaxf(fmaf(t[u].y, 0.7f, sp[u] * xx[u].y), 0.0f), 3.0f);
            o.z = fminf(fmaxf(fmaf(t[u].z, 0.7f, sp[u] * xx[u].z), 0.0f), 3.0f);
            o.w = fminf(fmaxf(fmaf(t[u].w, 0.7f, sp[u] * xx[u].w), 0.0f), 3.0f);
            ot4[g[u]] = o;                           // m13 copy pattern
        }
    }
}

extern "C" void kernel_launch(void* const* d_in, const int* in_sizes, int n_in,
                              void* d_out, int out_size, void* d_ws, size_t ws_size,
                              hipStream_t stream) {
    const float* x     = (const float*)d_in[0];  // spike_input        [1, 8192]
    const float* syn   = (const float*)d_in[1];  // synapse_states     [8192, 8192]
    const float* mp    = (const float*)d_in[2];  // membrane_potential [8192]
    const float* thr   = (const float*)d_in[3];  // adaptive_threshold [8192]
    const float* trace = (const float*)d_in[4];  // eligibility_trace  [8192, 8192]

    float* out = (float*)d_out;
    float* out_spikes = out;                     // [8192]
    float* out_vnew   = out + OUT_F;             // [8192]
    float* out_trace  = out + 2 * OUT_F;         // [8192, 8192]

    float* current = (float*)d_ws;               // [8192] accumulator

    hipMemsetAsync(current, 0, OUT_F * sizeof(float), stream);
    snn_gate_sweep<<<NTHREADS / 256, 256, 0, stream>>>(x, syn, current);
    snn_lif<<<OUT_F / 256, 256, 0, stream>>>(current, mp, thr, out_spikes, out_vnew);
    snn_trace_sweep<<<NTHREADS / 256, 256, 0, stream>>>(x, trace, out_spikes, out_trace);
}

// Round 8
// 595.841 us; speedup vs baseline: 1.0484x; 1.0484x over previous
//
#include <hip/hip_runtime.h>

// LogicGatedSNN v7: v5.1 with nontemporal load REMOVED from K1.
// Single-variable A/B vs v5.1 (585.3 us total, ~195 us kernel-side).
//
// Rationale: v1 (187 us, best) is the only version with zero NT accesses;
// every NT-containing version landed 195-220 us. NT loads bypass L2/MALL
// allocation and may demote the syn read stream. All other structural
// hypotheses (occupancy, CU-side traffic, fusion, DRAM address pattern)
// have been individually refuted in v2-v6.
//
//  K1 snn_matvec: wave-per-row gated row-sum + LIF. Regular loads.
//  K2 snn_trace: elementwise trace update, m13 copy pattern (regular
//     loads/stores), block owns 4 contiguous rows.

#define IN_F 8192
#define OUT_F 8192
#define SYN_THRESH 50.0f

typedef float vfloat4 __attribute__((ext_vector_type(4)));

// ---------------- K1: matvec + LIF (wave-per-row) ----------------
__global__ __launch_bounds__(256, 8) void snn_matvec(
    const float* __restrict__ x,      // [IN_F] spike_input (0/1)
    const float* __restrict__ syn,    // [OUT_F, IN_F]
    const float* __restrict__ mp,     // [OUT_F]
    const float* __restrict__ thr,    // [OUT_F]
    float* __restrict__ out_spikes,   // [OUT_F]
    float* __restrict__ out_vnew)     // [OUT_F]
{
    const int wave = threadIdx.x >> 6;
    const int lane = threadIdx.x & 63;
    const int row  = (blockIdx.x << 2) | wave;   // 4 rows per block
    const long long base = (long long)row * IN_F;

    const vfloat4* __restrict__ syn4 = (const vfloat4*)(syn + base);
    const vfloat4* __restrict__ x4   = (const vfloat4*)x;

    // 2048 float4 per row / 64 lanes = 32 per lane, in 8 chunks of 4
    // (bounded unroll keeps VGPR < 64 -> 8 waves/SIMD).
    float sum = 0.0f;
#pragma unroll 1
    for (int c = 0; c < 8; ++c) {
        vfloat4 s[4], xx[4];
#pragma unroll
        for (int u = 0; u < 4; ++u) {
            const int idx = (((c << 2) + u) << 6) | lane;   // coalesced
            s[u]  = syn4[idx];                              // REGULAR load
            xx[u] = x4[idx];                                // L1-resident
        }
#pragma unroll
        for (int u = 0; u < 4; ++u) {
            sum += ((s[u].x > SYN_THRESH) ? xx[u].x : 0.0f)
                 + ((s[u].y > SYN_THRESH) ? xx[u].y : 0.0f)
                 + ((s[u].z > SYN_THRESH) ? xx[u].z : 0.0f)
                 + ((s[u].w > SYN_THRESH) ? xx[u].w : 0.0f);
        }
    }

    // butterfly: all 64 lanes end with the row sum
#pragma unroll
    for (int off = 32; off > 0; off >>= 1)
        sum += __shfl_xor(sum, off, 64);

    if (lane == 0) {
        const float v     = mp[row] * 0.6f + sum;
        const float spike = (v >= thr[row]) ? 1.0f : 0.0f;
        out_spikes[row] = spike;
        out_vnew[row]   = v * (1.0f - spike) * 0.3f;
    }
}

// ---------------- K2: trace update (pure stream) ----------------
// Each block owns 4 contiguous rows = 8192 float4 (128 KB region).
// Row stride = 2048 float4: row-in-block = idx>>11, col = idx&2047.
__global__ __launch_bounds__(256, 8) void snn_trace(
    const float* __restrict__ x,        // [IN_F]
    const float* __restrict__ trace,    // [OUT_F, IN_F]
    const float* __restrict__ spikes,   // [OUT_F]  (from K1)
    float* __restrict__ out_trace)      // [OUT_F, IN_F]
{
    const long long blk4 = (long long)blockIdx.x * 8192;   // float4 units
    const vfloat4* __restrict__ tr4 = (const vfloat4*)trace + blk4;
    vfloat4* __restrict__ ot4       = (vfloat4*)out_trace + blk4;
    const vfloat4* __restrict__ x4  = (const vfloat4*)x;   // 2048 float4
    const int row0 = blockIdx.x << 2;
    const int tid  = threadIdx.x;

#pragma unroll 1
    for (int c = 0; c < 8; ++c) {
        vfloat4 t[4], xx[4];
        float sp[4];
#pragma unroll
        for (int u = 0; u < 4; ++u) {
            const int idx = (c << 10) | (u << 8) | tid;     // 0..8191, coalesced
            t[u]  = tr4[idx];
            xx[u] = x4[idx & 2047];                         // col within row
            sp[u] = spikes[row0 + (idx >> 11)];             // row within block
        }
#pragma unroll
        for (int u = 0; u < 4; ++u) {
            const int idx = (c << 10) | (u << 8) | tid;
            vfloat4 o;
            o.x = fminf(fmaxf(fmaf(t[u].x, 0.7f, sp[u] * xx[u].x), 0.0f), 3.0f);
            o.y = fminf(fmaxf(fmaf(t[u].y, 0.7f, sp[u] * xx[u].y), 0.0f), 3.0f);
            o.z = fminf(fmaxf(fmaf(t[u].z, 0.7f, sp[u] * xx[u].z), 0.0f), 3.0f);
            o.w = fminf(fmaxf(fmaf(t[u].w, 0.7f, sp[u] * xx[u].w), 0.0f), 3.0f);
            ot4[idx] = o;                                   // regular store (m13 pattern)
        }
    }
}

extern "C" void kernel_launch(void* const* d_in, const int* in_sizes, int n_in,
                              void* d_out, int out_size, void* d_ws, size_t ws_size,
                              hipStream_t stream) {
    const float* x     = (const float*)d_in[0];  // spike_input        [1, 8192]
    const float* syn   = (const float*)d_in[1];  // synapse_states     [8192, 8192]
    const float* mp    = (const float*)d_in[2];  // membrane_potential [8192]
    const float* thr   = (const float*)d_in[3];  // adaptive_threshold [8192]
    const float* trace = (const float*)d_in[4];  // eligibility_trace  [8192, 8192]

    float* out = (float*)d_out;
    float* out_spikes = out;                     // [8192]
    float* out_vnew   = out + OUT_F;             // [8192]
    float* out_trace  = out + 2 * OUT_F;         // [8192, 8192]

    snn_matvec<<<OUT_F / 4, 256, 0, stream>>>(
        x, syn, mp, thr, out_spikes, out_vnew);
    snn_trace<<<OUT_F / 4, 256, 0, stream>>>(
        x, trace, out_spikes, out_trace);
}